// Round 17
// baseline (249.880 us; speedup 1.0000x reference)
//
#include <hip/hip_runtime.h>
#include <hip/hip_bf16.h>

namespace {

constexpr int Bn      = 256;
constexpr int NNODES  = 64;
constexpr int NGROUPS = 16;
constexpr int L       = 64;
constexpr int C       = 32;
constexpr int GH      = 128;
constexpr int E1      = 262144;
constexpr int E2      = 32768;
constexpr int NROWS   = Bn * NNODES;   // 16384
constexpr int GROWS   = Bn * NGROUPS;  // 4096
constexpr int XROW    = 296;           // LDS row stride (288 data + 8 pad)

// ---------------- conv helpers ---------------------------------------------
template<int K, int LX>
__device__ __forceinline__ void convmax2(const float* __restrict__ xin_al,
                                         const float* __restrict__ wpa,
                                         const float* __restrict__ wpb,
                                         float& ma, float& mb)
{
    constexpr int PAD = (K - 1) / 2;
    constexpr int OFF = 3 - PAD;
    float wa[K], wb[K];
    #pragma unroll
    for (int i = 0; i < K; ++i) { wa[i] = wpa[i]; wb[i] = wpb[i]; }
    ma = -3.0e38f; mb = -3.0e38f;
    #pragma unroll
    for (int p0 = 0; p0 < LX; p0 += 16) {
        float xw[24];
        #pragma unroll
        for (int q = 0; q < 6; ++q) {
            const float4 v = *(const float4*)(xin_al + p0 + q * 4);
            xw[q * 4 + 0] = v.x; xw[q * 4 + 1] = v.y;
            xw[q * 4 + 2] = v.z; xw[q * 4 + 3] = v.w;
        }
        #pragma unroll
        for (int p = 0; p < 16; p += 2) {
            if (p0 + p + 1 < LX) {
                float sa0 = 0.f, sb0 = 0.f, sa1 = 0.f, sb1 = 0.f;
                #pragma unroll
                for (int i = 0; i < K; ++i) {
                    const float xv0 = xw[p + OFF + i];
                    const float xv1 = xw[p + 1 + OFF + i];
                    sa0 = fmaf(wa[i], xv0, sa0);
                    sb0 = fmaf(wb[i], xv0, sb0);
                    sa1 = fmaf(wa[i], xv1, sa1);
                    sb1 = fmaf(wb[i], xv1, sb1);
                }
                ma = fmaxf(fmaxf(sa0, sa1), ma);
                mb = fmaxf(fmaxf(sb0, sb1), mb);
            }
        }
    }
}

__device__ __forceinline__ void conv6_ch0(
    const float* __restrict__ xin_al,
    const float* __restrict__ w3a, const float* __restrict__ w3b,
    const float* __restrict__ w5a, const float* __restrict__ w5b,
    const float* __restrict__ w7a, const float* __restrict__ w7b,
    float& m3a, float& m3b, float& m5a, float& m5b, float& m7a, float& m7b)
{
    float a3[3], b3[3], a5[5], b5[5], a7[7], b7[7];
    #pragma unroll
    for (int i = 0; i < 3; ++i) { a3[i] = w3a[i]; b3[i] = w3b[i]; }
    #pragma unroll
    for (int i = 0; i < 5; ++i) { a5[i] = w5a[i]; b5[i] = w5b[i]; }
    #pragma unroll
    for (int i = 0; i < 7; ++i) { a7[i] = w7a[i]; b7[i] = w7b[i]; }
    m3a = m3b = m5a = m5b = m7a = m7b = -3.0e38f;
    #pragma unroll
    for (int p0 = 0; p0 < 64; p0 += 16) {
        float xw[24];
        #pragma unroll
        for (int q = 0; q < 6; ++q) {
            const float4 v = *(const float4*)(xin_al + p0 + q * 4);
            xw[q * 4 + 0] = v.x; xw[q * 4 + 1] = v.y;
            xw[q * 4 + 2] = v.z; xw[q * 4 + 3] = v.w;
        }
        #pragma unroll
        for (int p = 0; p < 16; p += 2) {
            float s3a0 = 0.f, s3b0 = 0.f, s3a1 = 0.f, s3b1 = 0.f;
            #pragma unroll
            for (int i = 0; i < 3; ++i) {
                const float xv0 = xw[p + 2 + i], xv1 = xw[p + 3 + i];
                s3a0 = fmaf(a3[i], xv0, s3a0); s3b0 = fmaf(b3[i], xv0, s3b0);
                s3a1 = fmaf(a3[i], xv1, s3a1); s3b1 = fmaf(b3[i], xv1, s3b1);
            }
            m3a = fmaxf(fmaxf(s3a0, s3a1), m3a);
            m3b = fmaxf(fmaxf(s3b0, s3b1), m3b);
            float s5a0 = 0.f, s5b0 = 0.f, s5a1 = 0.f, s5b1 = 0.f;
            #pragma unroll
            for (int i = 0; i < 5; ++i) {
                const float xv0 = xw[p + 1 + i], xv1 = xw[p + 2 + i];
                s5a0 = fmaf(a5[i], xv0, s5a0); s5b0 = fmaf(b5[i], xv0, s5b0);
                s5a1 = fmaf(a5[i], xv1, s5a1); s5b1 = fmaf(b5[i], xv1, s5b1);
            }
            m5a = fmaxf(fmaxf(s5a0, s5a1), m5a);
            m5b = fmaxf(fmaxf(s5b0, s5b1), m5b);
            float s7a0 = 0.f, s7b0 = 0.f, s7a1 = 0.f, s7b1 = 0.f;
            #pragma unroll
            for (int i = 0; i < 7; ++i) {
                const float xv0 = xw[p + 0 + i], xv1 = xw[p + 1 + i];
                s7a0 = fmaf(a7[i], xv0, s7a0); s7b0 = fmaf(b7[i], xv0, s7b0);
                s7a1 = fmaf(a7[i], xv1, s7a1); s7b1 = fmaf(b7[i], xv1, s7b1);
            }
            m7a = fmaxf(fmaxf(s7a0, s7a1), m7a);
            m7b = fmaxf(fmaxf(s7b0, s7b1), m7b);
        }
    }
}

// ---------------- K2: conv (blocks 0..2047) + CSR hist (blocks 2048..4351) --
__global__ __launch_bounds__(256) void k_conv_hist(
    const float* __restrict__ x1, const float* __restrict__ x2,
    const float* __restrict__ w3,  const float* __restrict__ b3,
    const float* __restrict__ w5,  const float* __restrict__ b5,
    const float* __restrict__ w7,  const float* __restrict__ b7,
    const float* __restrict__ tw3, const float* __restrict__ tb3,
    const float* __restrict__ tw5, const float* __restrict__ tb5,
    const float* __restrict__ tw7, const float* __restrict__ tb7,
    float* __restrict__ feats,
    const int* __restrict__ ei0, const int* __restrict__ ei1,
    const int* __restrict__ gei0, const int* __restrict__ gei1,
    int* __restrict__ cnt1, int* __restrict__ cnt2)
{
    __shared__ float xs[16 * XROW];
    const int t = threadIdx.x;             // 256
    if (blockIdx.x >= 2048) {
        const int gid = (blockIdx.x - 2048) * 256 + t;
        if (gid < 2 * E1) {
            const int eb = gid >= E1;
            const int le = gid - (eb ? E1 : 0);
            const int* ei = eb ? ei1 : ei0;
            atomicAdd(&cnt1[(eb ? NROWS : 0) + ei[E1 + le]], 1);
        } else {
            const int g2 = gid - 2 * E1;
            const int eb = g2 >= E2;
            const int le = g2 - (eb ? E2 : 0);
            const int* ei = eb ? gei1 : gei0;
            atomicAdd(&cnt2[(eb ? GROWS : 0) + ei[E2 + le]], 1);
        }
        return;
    }
    const int eb = blockIdx.x >> 10;       // 0,1
    const float* __restrict__ x = eb ? x2 : x1;
    const int row0 = (blockIdx.x & 1023) * 16;
    for (int idx = t; idx < 16 * 4 * 72; idx += 256) {
        const int r   = idx / 288;
        const int rem = idx - r * 288;
        const int c   = rem / 72;
        const int j   = rem - c * 72;
        const int l   = j - 3;
        float v = 0.f;
        if (l >= 0 && l < 64 - 2 * c)
            v = x[(size_t)(row0 + r) * 256 + c * 64 + l];
        xs[r * XROW + c * 72 + j] = v;
    }
    __syncthreads();

    const int rr  = t >> 4;
    const int cp  = t & 15;
    const int ch0 = cp * 2;
    const int row = row0 + rr;
    const int n   = row & (NNODES - 1);
    const int wc0 = n * C + ch0;
    const int wc1 = wc0 + 1;
    const float* xb0 = &xs[rr * XROW + 0 * 72];
    const float* xb1 = &xs[rr * XROW + 1 * 72];
    const float* xb2 = &xs[rr * XROW + 2 * 72];
    const float* xb3 = &xs[rr * XROW + 3 * 72];

    float* o = feats + (size_t)(eb * NROWS + row) * 192 + ch0;

    float m3a, m3b, m5a, m5b, m7a, m7b;
    conv6_ch0(xb0, w3 + wc0 * 3, w3 + wc1 * 3, w5 + wc0 * 5, w5 + wc1 * 5,
              w7 + wc0 * 7, w7 + wc1 * 7, m3a, m3b, m5a, m5b, m7a, m7b);
    *(float2*)(o + 0 * 32) = make_float2(fmaxf(m3a + b3[wc0], 0.f), fmaxf(m3b + b3[wc1], 0.f));
    *(float2*)(o + 1 * 32) = make_float2(fmaxf(m5a + b5[wc0], 0.f), fmaxf(m5b + b5[wc1], 0.f));
    *(float2*)(o + 2 * 32) = make_float2(fmaxf(m7a + b7[wc0], 0.f), fmaxf(m7b + b7[wc1], 0.f));

    float ma, mb;
    convmax2<3, 62>(xb1, tw3 + wc0 * 3, tw3 + wc1 * 3, ma, mb);
    *(float2*)(o + 3 * 32) = make_float2(fmaxf(ma + tb3[wc0], 0.f), fmaxf(mb + tb3[wc1], 0.f));
    convmax2<5, 60>(xb2, tw5 + wc0 * 5, tw5 + wc1 * 5, ma, mb);
    *(float2*)(o + 4 * 32) = make_float2(fmaxf(ma + tb5[wc0], 0.f), fmaxf(mb + tb5[wc1], 0.f));
    convmax2<7, 58>(xb3, tw7 + wc0 * 7, tw7 + wc1 * 7, ma, mb);
    *(float2*)(o + 5 * 32) = make_float2(fmaxf(ma + tb7[wc0], 0.f), fmaxf(mb + tb7[wc1], 0.f));
}

// ---------------- K5: ff_lower 32-rows, 4 cols x 4 rows/thread + CSR fill ---
// ff block (0..1023): nb = b-tile of 32, n = node.
// thread: c = t&31 -> cols {c, c+32, c+64, c+96}; rg = t>>5 -> rows rg*4..rg*4+3.
// Per k-quad per wave: 4 LDS b128 (2-addr broadcast) + 16 weight loads + 64 fma.
__global__ __launch_bounds__(256) void k_ff_lower_fill(
    const float* __restrict__ feats, const float* __restrict__ ffw,
    const float* __restrict__ ffb, const float* __restrict__ lw,
    float* __restrict__ hw,
    const int* __restrict__ ei0, const int* __restrict__ ei1,
    const int* __restrict__ gei0, const int* __restrict__ gei1,
    int* __restrict__ cur1, int* __restrict__ esrc1,
    int* __restrict__ cur2, int* __restrict__ esrc2)
{
    __shared__ float fs[32 * 192];         // 24.5 KB
    __shared__ float h0s[32 * 128];        // 16 KB
    const int t = threadIdx.x;
    if (blockIdx.x >= 1024) {
        const int gid = (blockIdx.x - 1024) * 256 + t;
        if (gid < 2 * E1) {
            const int eb = gid >= E1;
            const int le = gid - (eb ? E1 : 0);
            const int* ei = eb ? ei1 : ei0;
            const int s = ei[le];
            const int d = ei[E1 + le];
            const int pos = atomicAdd(&cur1[(eb ? NROWS : 0) + d], 1);
            esrc1[pos] = s;
        } else {
            const int g2 = gid - 2 * E1;
            const int eb = g2 >= E2;
            const int le = g2 - (eb ? E2 : 0);
            const int* ei = eb ? gei1 : gei0;
            const int s = ei[le];
            const int d = ei[E2 + le];
            const int pos = atomicAdd(&cur2[(eb ? GROWS : 0) + d], 1);
            esrc2[pos] = s;
        }
        return;
    }
    const int nb = blockIdx.x >> 6;        // 0..15 (b-tile of 32 over 512)
    const int n  = blockIdx.x & 63;
    const int c  = t & 31;                 // cols c + 32*m
    const int rg = t >> 5;                 // 0..7 -> rows rg*4..rg*4+3
    {
        float4* d4 = (float4*)fs;
        for (int i = t; i < 32 * 48; i += 256) {
            const int r = i / 48, c4 = i - r * 48;
            d4[i] = *(const float4*)(feats + ((size_t)(nb * 32 + r) * 64 + n) * 192 + c4 * 4);
        }
    }
    __syncthreads();
    // phase 1: h0 = relu(feats @ ffw + b), K=192
    {
        const float* w = ffw + (size_t)n * 192 * 128 + c;
        float acc[4][4];
        #pragma unroll
        for (int j = 0; j < 4; ++j)
            #pragma unroll
            for (int m = 0; m < 4; ++m) acc[j][m] = 0.f;
        #pragma unroll 2
        for (int f = 0; f < 192; f += 4) {
            float wv[4][4];
            #pragma unroll
            for (int k = 0; k < 4; ++k)
                #pragma unroll
                for (int m = 0; m < 4; ++m)
                    wv[k][m] = w[(f + k) * 128 + m * 32];
            #pragma unroll
            for (int j = 0; j < 4; ++j) {
                const float4 xv = *(const float4*)(fs + (rg * 4 + j) * 192 + f);
                #pragma unroll
                for (int m = 0; m < 4; ++m) {
                    acc[j][m] = fmaf(xv.x, wv[0][m], acc[j][m]);
                    acc[j][m] = fmaf(xv.y, wv[1][m], acc[j][m]);
                    acc[j][m] = fmaf(xv.z, wv[2][m], acc[j][m]);
                    acc[j][m] = fmaf(xv.w, wv[3][m], acc[j][m]);
                }
            }
        }
        float bias[4];
        #pragma unroll
        for (int m = 0; m < 4; ++m) bias[m] = ffb[n * 128 + c + m * 32];
        #pragma unroll
        for (int j = 0; j < 4; ++j)
            #pragma unroll
            for (int m = 0; m < 4; ++m)
                h0s[(rg * 4 + j) * 128 + c + m * 32] = fmaxf(acc[j][m] + bias[m], 0.f);
    }
    __syncthreads();
    // phase 2: hw = h0 @ lower_w, K=128
    {
        const float* w = lw + c;
        float acc[4][4];
        #pragma unroll
        for (int j = 0; j < 4; ++j)
            #pragma unroll
            for (int m = 0; m < 4; ++m) acc[j][m] = 0.f;
        #pragma unroll 2
        for (int f = 0; f < 128; f += 4) {
            float wv[4][4];
            #pragma unroll
            for (int k = 0; k < 4; ++k)
                #pragma unroll
                for (int m = 0; m < 4; ++m)
                    wv[k][m] = w[(f + k) * 128 + m * 32];
            #pragma unroll
            for (int j = 0; j < 4; ++j) {
                const float4 xv = *(const float4*)(h0s + (rg * 4 + j) * 128 + f);
                #pragma unroll
                for (int m = 0; m < 4; ++m) {
                    acc[j][m] = fmaf(xv.x, wv[0][m], acc[j][m]);
                    acc[j][m] = fmaf(xv.y, wv[1][m], acc[j][m]);
                    acc[j][m] = fmaf(xv.z, wv[2][m], acc[j][m]);
                    acc[j][m] = fmaf(xv.w, wv[3][m], acc[j][m]);
                }
            }
        }
        #pragma unroll
        for (int j = 0; j < 4; ++j) {
            const int row = nb * 32 + rg * 4 + j;
            #pragma unroll
            for (int m = 0; m < 4; ++m)
                hw[((size_t)row * 64 + n) * 128 + c + m * 32] = acc[j][m];
        }
    }
}

// ---------------- CSR small kernels -----------------------------------------
__global__ void k_zero_i(int* __restrict__ p, int n) {
    const int i = blockIdx.x * blockDim.x + threadIdx.x;
    if (i < n) p[i] = 0;
}
__global__ __launch_bounds__(256) void k_scan_bsum_all(
    const int* __restrict__ cnt1, const int* __restrict__ cnt2,
    int* __restrict__ bsum1, int* __restrict__ bsum2)
{
    const int blk = blockIdx.x, t = threadIdx.x;
    const int* cnt; int* bsum; int lblk;
    if (blk < 32) { cnt = cnt1; bsum = bsum1; lblk = blk; }
    else          { cnt = cnt2; bsum = bsum2; lblk = blk - 32; }
    const int4 v = ((const int4*)cnt)[lblk * 256 + t];
    int s = v.x + v.y + v.z + v.w;
    #pragma unroll
    for (int off = 32; off > 0; off >>= 1) s += __shfl_down(s, off);
    __shared__ int wsum[4];
    if ((t & 63) == 0) wsum[t >> 6] = s;
    __syncthreads();
    if (t == 0) bsum[lblk] = wsum[0] + wsum[1] + wsum[2] + wsum[3];
}
__global__ __launch_bounds__(256) void k_scan_final_all(
    const int* __restrict__ cnt1, const int* __restrict__ bsum1,
    int* __restrict__ offs1, int* __restrict__ cur1, float* __restrict__ dinv1,
    const int* __restrict__ cnt2, const int* __restrict__ bsum2,
    int* __restrict__ offs2, int* __restrict__ cur2, float* __restrict__ dinv2)
{
    const int blk = blockIdx.x, t = threadIdx.x;
    const int* cnt; const int* bsum; int* offs; int* cur; float* dinv;
    int n, nb, lblk;
    if (blk < 32) { cnt = cnt1; bsum = bsum1; offs = offs1; cur = cur1; dinv = dinv1;
                    n = 2 * NROWS; nb = 32; lblk = blk; }
    else          { cnt = cnt2; bsum = bsum2; offs = offs2; cur = cur2; dinv = dinv2;
                    n = 2 * GROWS; nb = 8; lblk = blk - 32; }
    int base = 0;
    for (int i = 0; i < lblk; ++i) base += bsum[i];
    const int4 v = ((const int4*)cnt)[lblk * 256 + t];
    const int s = v.x + v.y + v.z + v.w;
    int sc = s;
    #pragma unroll
    for (int off = 1; off < 64; off <<= 1) {
        const int u = __shfl_up(sc, off);
        if ((t & 63) >= off) sc += u;
    }
    __shared__ int wsum[4];
    if ((t & 63) == 63) wsum[t >> 6] = sc;
    __syncthreads();
    int wbase = 0;
    for (int wv = 0; wv < (t >> 6); ++wv) wbase += wsum[wv];
    int o0 = base + wbase + sc - s;
    const int gi = lblk * 1024 + t * 4;
    offs[gi + 0] = o0; cur[gi + 0] = o0; dinv[gi + 0] = rsqrtf(1.f + (float)v.x); o0 += v.x;
    offs[gi + 1] = o0; cur[gi + 1] = o0; dinv[gi + 1] = rsqrtf(1.f + (float)v.y); o0 += v.y;
    offs[gi + 2] = o0; cur[gi + 2] = o0; dinv[gi + 2] = rsqrtf(1.f + (float)v.z); o0 += v.z;
    offs[gi + 3] = o0; cur[gi + 3] = o0; dinv[gi + 3] = rsqrtf(1.f + (float)v.w); o0 += v.w;
    if (lblk == nb - 1 && t == 255) offs[n] = o0;
}

// ---------------- GCN gather (combined 2n rows) -----------------------------
__global__ __launch_bounds__(128) void k_gcn_gather(
    const int* __restrict__ offs, const int* __restrict__ esrc,
    const float* __restrict__ hw, const float* __restrict__ dinv,
    const float* __restrict__ bias, float* __restrict__ out, int n)
{
    const int d = blockIdx.x;
    const int t = threadIdx.x;             // 128
    const int sbase = (d >= n) ? n : 0;
    const int e0 = offs[d], e1 = offs[d + 1];
    const float dd = dinv[d];
    float a0 = hw[(size_t)d * 128 + t] * dd;
    float a1 = 0.f, a2 = 0.f, a3 = 0.f;
    int j = e0;
    for (; j + 3 < e1; j += 4) {
        const int s0 = sbase + esrc[j],     s1 = sbase + esrc[j + 1];
        const int s2 = sbase + esrc[j + 2], s3 = sbase + esrc[j + 3];
        a0 = fmaf(hw[(size_t)s0 * 128 + t], dinv[s0], a0);
        a1 = fmaf(hw[(size_t)s1 * 128 + t], dinv[s1], a1);
        a2 = fmaf(hw[(size_t)s2 * 128 + t], dinv[s2], a2);
        a3 = fmaf(hw[(size_t)s3 * 128 + t], dinv[s3], a3);
    }
    for (; j < e1; ++j) {
        const int s = sbase + esrc[j];
        a0 = fmaf(hw[(size_t)s * 128 + t], dinv[s], a0);
    }
    const float acc = (a0 + a1) + (a2 + a3);
    out[(size_t)d * 128 + t] = fmaf(acc, dd, bias[t]);
}

// ---------------- fused agg(512->128) + upper(128x128) ---------------------
__global__ __launch_bounds__(256) void k_aggup(
    const float* __restrict__ h, const float* __restrict__ aggw,
    const float* __restrict__ aggb, const float* __restrict__ uw,
    float* __restrict__ hgw)
{
    const int bt = blockIdx.x >> 4;        // 0..127
    const int g  = blockIdx.x & 15;
    const int t  = threadIdx.x;
    const int o  = t & 127;
    const int hf = t >> 7;                 // 0..1
    __shared__ float fs[4 * 512];
    __shared__ float red[2][4][128];
    __shared__ float hgs[4][128];
    {
        const int b0 = bt * 4;
        float4* dst = (float4*)fs;
        for (int i = t; i < 4 * 128; i += 256) {
            const int r = i >> 7;
            const int q = i & 127;
            dst[i] = *(const float4*)(h + ((size_t)(b0 + r) * 64 + g * 4) * 128 + q * 4);
        }
    }
    __syncthreads();
    {
        const float* w = aggw + (size_t)g * 512 * 128 + (size_t)hf * 256 * 128 + o;
        float a0 = 0.f, a1 = 0.f, a2 = 0.f, a3 = 0.f;
        const float* x0 = fs + 0 * 512 + hf * 256;
        const float* x1 = fs + 1 * 512 + hf * 256;
        const float* x2 = fs + 2 * 512 + hf * 256;
        const float* x3 = fs + 3 * 512 + hf * 256;
        #pragma unroll 8
        for (int f = 0; f < 256; ++f) {
            const float wv = w[f * 128];
            a0 = fmaf(x0[f], wv, a0);
            a1 = fmaf(x1[f], wv, a1);
            a2 = fmaf(x2[f], wv, a2);
            a3 = fmaf(x3[f], wv, a3);
        }
        red[hf][0][o] = a0; red[hf][1][o] = a1; red[hf][2][o] = a2; red[hf][3][o] = a3;
    }
    __syncthreads();
    if (t < 128) {
        const float bias = aggb[g * 128 + t];
        #pragma unroll
        for (int r = 0; r < 4; ++r)
            hgs[r][t] = red[0][r][t] + red[1][r][t] + bias;
    }
    __syncthreads();
    {
        const float* w = uw + o;
        float a0 = 0.f, a1 = 0.f;
        #pragma unroll 2
        for (int f = 0; f < 128; f += 4) {
            const float w0 = w[(f + 0) * 128];
            const float w1 = w[(f + 1) * 128];
            const float w2 = w[(f + 2) * 128];
            const float w3_ = w[(f + 3) * 128];
            const float4 xv0 = *(const float4*)(&hgs[hf * 2 + 0][f]);
            const float4 xv1 = *(const float4*)(&hgs[hf * 2 + 1][f]);
            a0 = fmaf(xv0.x, w0, a0); a0 = fmaf(xv0.y, w1, a0);
            a0 = fmaf(xv0.z, w2, a0); a0 = fmaf(xv0.w, w3_, a0);
            a1 = fmaf(xv1.x, w0, a1); a1 = fmaf(xv1.y, w1, a1);
            a1 = fmaf(xv1.z, w2, a1); a1 = fmaf(xv1.w, w3_, a1);
        }
        const int r0g = (bt * 4 + hf * 2) * 16 + g;
        hgw[(size_t)r0g * 128 + o] = a0;
        hgw[(size_t)(r0g + 16) * 128 + o] = a1;
    }
}

// ---------------- fused gather2 + relu + disc(256->128,relu) ---------------
__global__ __launch_bounds__(256) void k_gdisc(
    const int* __restrict__ offs, const int* __restrict__ esrc,
    const float* __restrict__ hgw, const float* __restrict__ dinv,
    const float* __restrict__ ub,
    const float* __restrict__ dw, const float* __restrict__ db,
    float* __restrict__ dd)
{
    const int bt = blockIdx.x >> 4;        // 0..63
    const int g  = blockIdx.x & 15;
    const int t  = threadIdx.x;
    const int o  = t & 127;
    const int hf = t >> 7;
    __shared__ float fsA[2][8][128];
    __shared__ float fs[4][256];
    __shared__ float red[2][4][128];

    for (int r = 0; r < 8; ++r) {
        const int bi = r >> 1, eb = r & 1;
        const int sbase = eb ? GROWS : 0;
        const int drow = sbase + (bt * 4 + bi) * 16 + g;
        const int e0 = offs[drow], e1 = offs[drow + 1];
        float acc  = (hf == 0) ? hgw[(size_t)drow * 128 + o] * dinv[drow] : 0.f;
        float acc2 = 0.f;
        int jj = e0 + hf;
        for (; jj + 2 < e1; jj += 4) {
            const int s0 = sbase + esrc[jj];
            const int s1 = sbase + esrc[jj + 2];
            acc  = fmaf(hgw[(size_t)s0 * 128 + o], dinv[s0], acc);
            acc2 = fmaf(hgw[(size_t)s1 * 128 + o], dinv[s1], acc2);
        }
        for (; jj < e1; jj += 2) {
            const int s = sbase + esrc[jj];
            acc = fmaf(hgw[(size_t)s * 128 + o], dinv[s], acc);
        }
        fsA[hf][r][o] = acc + acc2;
    }
    __syncthreads();
    for (int idx = t; idx < 1024; idx += 256) {
        const int r = idx >> 7, oc = idx & 127;
        const int bi = r >> 1, eb = r & 1;
        const int sbase = eb ? GROWS : 0;
        const int drow = sbase + (bt * 4 + bi) * 16 + g;
        fs[bi][eb * 128 + oc] =
            fmaxf(fmaf(fsA[0][r][oc] + fsA[1][r][oc], dinv[drow], ub[oc]), 0.f);
    }
    __syncthreads();
    {
        const float* w = dw + (size_t)g * 256 * 128 + (size_t)hf * 128 * 128 + o;
        float a0 = 0.f, a1 = 0.f, a2 = 0.f, a3 = 0.f;
        const float* x0 = &fs[0][hf * 128];
        const float* x1 = &fs[1][hf * 128];
        const float* x2 = &fs[2][hf * 128];
        const float* x3 = &fs[3][hf * 128];
        #pragma unroll 8
        for (int f = 0; f < 128; ++f) {
            const float wv = w[f * 128];
            a0 = fmaf(x0[f], wv, a0);
            a1 = fmaf(x1[f], wv, a1);
            a2 = fmaf(x2[f], wv, a2);
            a3 = fmaf(x3[f], wv, a3);
        }
        red[hf][0][o] = a0; red[hf][1][o] = a1; red[hf][2][o] = a2; red[hf][3][o] = a3;
    }
    __syncthreads();
    if (t < 128) {
        const float bias = db[g * 128 + t];
        #pragma unroll
        for (int r = 0; r < 4; ++r) {
            const int b = bt * 4 + r;
            dd[(size_t)b * 2048 + g * 128 + t] =
                fmaxf(red[0][r][t] + red[1][r][t] + bias, 0.f);
        }
    }
}

// ---------------- final fc 2048->64 -----------------------------------------
__global__ __launch_bounds__(256) void k_fc(
    const float* __restrict__ dd, const float* __restrict__ fcw,
    const float* __restrict__ fcb, float* __restrict__ out)
{
    const int b = blockIdx.x;
    const int t = threadIdx.x;
    const int o = t & 63;
    const int k = t >> 6;
    __shared__ float ds[2048];
    __shared__ float red[4][64];
    for (int i = t; i < 2048; i += 256) ds[i] = dd[(size_t)b * 2048 + i];
    __syncthreads();
    const float* w  = fcw + (k * 512) * 64 + o;
    const float* xr = ds + k * 512;
    float a0 = 0.f, a1 = 0.f, a2 = 0.f, a3 = 0.f;
    #pragma unroll 4
    for (int f = 0; f < 512; f += 4) {
        a0 = fmaf(xr[f + 0], w[(f + 0) * 64], a0);
        a1 = fmaf(xr[f + 1], w[(f + 1) * 64], a1);
        a2 = fmaf(xr[f + 2], w[(f + 2) * 64], a2);
        a3 = fmaf(xr[f + 3], w[(f + 3) * 64], a3);
    }
    red[k][o] = (a0 + a1) + (a2 + a3);
    __syncthreads();
    if (t < 64)
        out[(size_t)b * 64 + t] = ((red[0][t] + red[1][t]) + (red[2][t] + red[3][t])) + fcb[t];
}

} // namespace

extern "C" void kernel_launch(void* const* d_in, const int* in_sizes, int n_in,
                              void* d_out, int out_size, void* d_ws, size_t ws_size,
                              hipStream_t stream)
{
    const float* x1 = (const float*)d_in[0];
    const float* x2 = (const float*)d_in[1];
    const int* ei0  = (const int*)d_in[2];
    const int* ei1  = (const int*)d_in[3];
    const int* gei0 = (const int*)d_in[4];
    const int* gei1 = (const int*)d_in[5];
    const float* conv_w3 = (const float*)d_in[6];
    const float* conv_b3 = (const float*)d_in[7];
    const float* conv_w5 = (const float*)d_in[8];
    const float* conv_b5 = (const float*)d_in[9];
    const float* conv_w7 = (const float*)d_in[10];
    const float* conv_b7 = (const float*)d_in[11];
    const float* tconv_w3 = (const float*)d_in[12];
    const float* tconv_b3 = (const float*)d_in[13];
    const float* tconv_w5 = (const float*)d_in[14];
    const float* tconv_b5 = (const float*)d_in[15];
    const float* tconv_w7 = (const float*)d_in[16];
    const float* tconv_b7 = (const float*)d_in[17];
    const float* ff_w    = (const float*)d_in[18];
    const float* ff_b    = (const float*)d_in[19];
    const float* lower_w = (const float*)d_in[20];
    const float* lower_b = (const float*)d_in[21];
    const float* upper_w = (const float*)d_in[22];
    const float* upper_b = (const float*)d_in[23];
    const float* agg_w   = (const float*)d_in[24];
    const float* agg_b   = (const float*)d_in[25];
    const float* disc_w  = (const float*)d_in[26];
    const float* disc_b  = (const float*)d_in[27];
    const float* fc_w    = (const float*)d_in[28];
    const float* fc_b    = (const float*)d_in[29];

    float* ws = (float*)d_ws;
    float* f_feats = ws;                          // 6291456
    float* f_hw    = ws + 10485760;               // 4194304
    float* f_gout  = ws + 14680064;               // 4194304
    float* f_hgw   = ws + 19922944;               // 1048576
    float* f_dd    = ws + 22020096;               // 524288
    float* f_dinv1 = ws + 22544384;               // 32768
    float* f_dinv2 = ws + 22577152;               // 8192
    int* ip    = (int*)(ws + 22585344);
    int* cnt1  = ip;                              // 32768
    int* cnt2  = cnt1 + 2 * NROWS;                // 8192
    int* offs1 = cnt2 + 2 * GROWS;                // 32769
    int* cur1  = offs1 + 2 * NROWS + 1;           // 32768
    int* esrc1 = cur1 + 2 * NROWS;                // 524288
    int* offs2 = esrc1 + 2 * E1;                  // 8193
    int* cur2  = offs2 + 2 * GROWS + 1;           // 8192
    int* esrc2 = cur2 + 2 * GROWS;                // 65536
    int* bsum1 = esrc2 + 2 * E2;                  // 32
    int* bsum2 = bsum1 + 32;                      // 8

    // 9 dispatches total
    k_zero_i<<<(2 * NROWS + 2 * GROWS) / 256, 256, 0, stream>>>(cnt1, 2 * NROWS + 2 * GROWS);
    k_conv_hist<<<2048 + (2 * E1 + 2 * E2) / 256, 256, 0, stream>>>(x1, x2,
        conv_w3, conv_b3, conv_w5, conv_b5, conv_w7, conv_b7,
        tconv_w3, tconv_b3, tconv_w5, tconv_b5, tconv_w7, tconv_b7, f_feats,
        ei0, ei1, gei0, gei1, cnt1, cnt2);
    k_scan_bsum_all<<<40, 256, 0, stream>>>(cnt1, cnt2, bsum1, bsum2);
    k_scan_final_all<<<40, 256, 0, stream>>>(cnt1, bsum1, offs1, cur1, f_dinv1,
                                             cnt2, bsum2, offs2, cur2, f_dinv2);
    k_ff_lower_fill<<<1024 + (2 * E1 + 2 * E2) / 256, 256, 0, stream>>>(
        f_feats, ff_w, ff_b, lower_w, f_hw,
        ei0, ei1, gei0, gei1, cur1, esrc1, cur2, esrc2);
    k_gcn_gather<<<2 * NROWS, 128, 0, stream>>>(offs1, esrc1, f_hw, f_dinv1,
                                                lower_b, f_gout, NROWS);
    k_aggup<<<2048, 256, 0, stream>>>(f_gout, agg_w, agg_b, upper_w, f_hgw);
    k_gdisc<<<1024, 256, 0, stream>>>(offs2, esrc2, f_hgw, f_dinv2, upper_b,
                                      disc_w, disc_b, f_dd);
    k_fc<<<Bn, 256, 0, stream>>>(f_dd, fc_w, fc_b, (float*)d_out);
}

// Round 18
// 242.085 us; speedup vs baseline: 1.0322x; 1.0322x over previous
//
#include <hip/hip_runtime.h>
#include <hip/hip_bf16.h>

namespace {

constexpr int Bn      = 256;
constexpr int NNODES  = 64;
constexpr int NGROUPS = 16;
constexpr int L       = 64;
constexpr int C       = 32;
constexpr int GH      = 128;
constexpr int E1      = 262144;
constexpr int E2      = 32768;
constexpr int NROWS   = Bn * NNODES;   // 16384
constexpr int GROWS   = Bn * NGROUPS;  // 4096
constexpr int XROW    = 296;           // LDS row stride (288 data + 8 pad)

// ---------------- conv helpers ---------------------------------------------
template<int K, int LX>
__device__ __forceinline__ void convmax2(const float* __restrict__ xin_al,
                                         const float* __restrict__ wpa,
                                         const float* __restrict__ wpb,
                                         float& ma, float& mb)
{
    constexpr int PAD = (K - 1) / 2;
    constexpr int OFF = 3 - PAD;
    float wa[K], wb[K];
    #pragma unroll
    for (int i = 0; i < K; ++i) { wa[i] = wpa[i]; wb[i] = wpb[i]; }
    ma = -3.0e38f; mb = -3.0e38f;
    #pragma unroll
    for (int p0 = 0; p0 < LX; p0 += 16) {
        float xw[24];
        #pragma unroll
        for (int q = 0; q < 6; ++q) {
            const float4 v = *(const float4*)(xin_al + p0 + q * 4);
            xw[q * 4 + 0] = v.x; xw[q * 4 + 1] = v.y;
            xw[q * 4 + 2] = v.z; xw[q * 4 + 3] = v.w;
        }
        #pragma unroll
        for (int p = 0; p < 16; p += 2) {
            if (p0 + p + 1 < LX) {
                float sa0 = 0.f, sb0 = 0.f, sa1 = 0.f, sb1 = 0.f;
                #pragma unroll
                for (int i = 0; i < K; ++i) {
                    const float xv0 = xw[p + OFF + i];
                    const float xv1 = xw[p + 1 + OFF + i];
                    sa0 = fmaf(wa[i], xv0, sa0);
                    sb0 = fmaf(wb[i], xv0, sb0);
                    sa1 = fmaf(wa[i], xv1, sa1);
                    sb1 = fmaf(wb[i], xv1, sb1);
                }
                ma = fmaxf(fmaxf(sa0, sa1), ma);
                mb = fmaxf(fmaxf(sb0, sb1), mb);
            }
        }
    }
}

__device__ __forceinline__ void conv6_ch0(
    const float* __restrict__ xin_al,
    const float* __restrict__ w3a, const float* __restrict__ w3b,
    const float* __restrict__ w5a, const float* __restrict__ w5b,
    const float* __restrict__ w7a, const float* __restrict__ w7b,
    float& m3a, float& m3b, float& m5a, float& m5b, float& m7a, float& m7b)
{
    float a3[3], b3[3], a5[5], b5[5], a7[7], b7[7];
    #pragma unroll
    for (int i = 0; i < 3; ++i) { a3[i] = w3a[i]; b3[i] = w3b[i]; }
    #pragma unroll
    for (int i = 0; i < 5; ++i) { a5[i] = w5a[i]; b5[i] = w5b[i]; }
    #pragma unroll
    for (int i = 0; i < 7; ++i) { a7[i] = w7a[i]; b7[i] = w7b[i]; }
    m3a = m3b = m5a = m5b = m7a = m7b = -3.0e38f;
    #pragma unroll
    for (int p0 = 0; p0 < 64; p0 += 16) {
        float xw[24];
        #pragma unroll
        for (int q = 0; q < 6; ++q) {
            const float4 v = *(const float4*)(xin_al + p0 + q * 4);
            xw[q * 4 + 0] = v.x; xw[q * 4 + 1] = v.y;
            xw[q * 4 + 2] = v.z; xw[q * 4 + 3] = v.w;
        }
        #pragma unroll
        for (int p = 0; p < 16; p += 2) {
            float s3a0 = 0.f, s3b0 = 0.f, s3a1 = 0.f, s3b1 = 0.f;
            #pragma unroll
            for (int i = 0; i < 3; ++i) {
                const float xv0 = xw[p + 2 + i], xv1 = xw[p + 3 + i];
                s3a0 = fmaf(a3[i], xv0, s3a0); s3b0 = fmaf(b3[i], xv0, s3b0);
                s3a1 = fmaf(a3[i], xv1, s3a1); s3b1 = fmaf(b3[i], xv1, s3b1);
            }
            m3a = fmaxf(fmaxf(s3a0, s3a1), m3a);
            m3b = fmaxf(fmaxf(s3b0, s3b1), m3b);
            float s5a0 = 0.f, s5b0 = 0.f, s5a1 = 0.f, s5b1 = 0.f;
            #pragma unroll
            for (int i = 0; i < 5; ++i) {
                const float xv0 = xw[p + 1 + i], xv1 = xw[p + 2 + i];
                s5a0 = fmaf(a5[i], xv0, s5a0); s5b0 = fmaf(b5[i], xv0, s5b0);
                s5a1 = fmaf(a5[i], xv1, s5a1); s5b1 = fmaf(b5[i], xv1, s5b1);
            }
            m5a = fmaxf(fmaxf(s5a0, s5a1), m5a);
            m5b = fmaxf(fmaxf(s5b0, s5b1), m5b);
            float s7a0 = 0.f, s7b0 = 0.f, s7a1 = 0.f, s7b1 = 0.f;
            #pragma unroll
            for (int i = 0; i < 7; ++i) {
                const float xv0 = xw[p + 0 + i], xv1 = xw[p + 1 + i];
                s7a0 = fmaf(a7[i], xv0, s7a0); s7b0 = fmaf(b7[i], xv0, s7b0);
                s7a1 = fmaf(a7[i], xv1, s7a1); s7b1 = fmaf(b7[i], xv1, s7b1);
            }
            m7a = fmaxf(fmaxf(s7a0, s7a1), m7a);
            m7b = fmaxf(fmaxf(s7b0, s7b1), m7b);
        }
    }
}

// ---------------- K2: conv (blocks 0..2047) + CSR hist (blocks 2048..4351) --
__global__ __launch_bounds__(256) void k_conv_hist(
    const float* __restrict__ x1, const float* __restrict__ x2,
    const float* __restrict__ w3,  const float* __restrict__ b3,
    const float* __restrict__ w5,  const float* __restrict__ b5,
    const float* __restrict__ w7,  const float* __restrict__ b7,
    const float* __restrict__ tw3, const float* __restrict__ tb3,
    const float* __restrict__ tw5, const float* __restrict__ tb5,
    const float* __restrict__ tw7, const float* __restrict__ tb7,
    float* __restrict__ feats,
    const int* __restrict__ ei0, const int* __restrict__ ei1,
    const int* __restrict__ gei0, const int* __restrict__ gei1,
    int* __restrict__ cnt1, int* __restrict__ cnt2)
{
    __shared__ float xs[16 * XROW];
    const int t = threadIdx.x;             // 256
    if (blockIdx.x >= 2048) {
        const int gid = (blockIdx.x - 2048) * 256 + t;
        if (gid < 2 * E1) {
            const int eb = gid >= E1;
            const int le = gid - (eb ? E1 : 0);
            const int* ei = eb ? ei1 : ei0;
            atomicAdd(&cnt1[(eb ? NROWS : 0) + ei[E1 + le]], 1);
        } else {
            const int g2 = gid - 2 * E1;
            const int eb = g2 >= E2;
            const int le = g2 - (eb ? E2 : 0);
            const int* ei = eb ? gei1 : gei0;
            atomicAdd(&cnt2[(eb ? GROWS : 0) + ei[E2 + le]], 1);
        }
        return;
    }
    const int eb = blockIdx.x >> 10;       // 0,1
    const float* __restrict__ x = eb ? x2 : x1;
    const int row0 = (blockIdx.x & 1023) * 16;
    for (int idx = t; idx < 16 * 4 * 72; idx += 256) {
        const int r   = idx / 288;
        const int rem = idx - r * 288;
        const int c   = rem / 72;
        const int j   = rem - c * 72;
        const int l   = j - 3;
        float v = 0.f;
        if (l >= 0 && l < 64 - 2 * c)
            v = x[(size_t)(row0 + r) * 256 + c * 64 + l];
        xs[r * XROW + c * 72 + j] = v;
    }
    __syncthreads();

    const int rr  = t >> 4;
    const int cp  = t & 15;
    const int ch0 = cp * 2;
    const int row = row0 + rr;
    const int n   = row & (NNODES - 1);
    const int wc0 = n * C + ch0;
    const int wc1 = wc0 + 1;
    const float* xb0 = &xs[rr * XROW + 0 * 72];
    const float* xb1 = &xs[rr * XROW + 1 * 72];
    const float* xb2 = &xs[rr * XROW + 2 * 72];
    const float* xb3 = &xs[rr * XROW + 3 * 72];

    float* o = feats + (size_t)(eb * NROWS + row) * 192 + ch0;

    float m3a, m3b, m5a, m5b, m7a, m7b;
    conv6_ch0(xb0, w3 + wc0 * 3, w3 + wc1 * 3, w5 + wc0 * 5, w5 + wc1 * 5,
              w7 + wc0 * 7, w7 + wc1 * 7, m3a, m3b, m5a, m5b, m7a, m7b);
    *(float2*)(o + 0 * 32) = make_float2(fmaxf(m3a + b3[wc0], 0.f), fmaxf(m3b + b3[wc1], 0.f));
    *(float2*)(o + 1 * 32) = make_float2(fmaxf(m5a + b5[wc0], 0.f), fmaxf(m5b + b5[wc1], 0.f));
    *(float2*)(o + 2 * 32) = make_float2(fmaxf(m7a + b7[wc0], 0.f), fmaxf(m7b + b7[wc1], 0.f));

    float ma, mb;
    convmax2<3, 62>(xb1, tw3 + wc0 * 3, tw3 + wc1 * 3, ma, mb);
    *(float2*)(o + 3 * 32) = make_float2(fmaxf(ma + tb3[wc0], 0.f), fmaxf(mb + tb3[wc1], 0.f));
    convmax2<5, 60>(xb2, tw5 + wc0 * 5, tw5 + wc1 * 5, ma, mb);
    *(float2*)(o + 4 * 32) = make_float2(fmaxf(ma + tb5[wc0], 0.f), fmaxf(mb + tb5[wc1], 0.f));
    convmax2<7, 58>(xb3, tw7 + wc0 * 7, tw7 + wc1 * 7, ma, mb);
    *(float2*)(o + 5 * 32) = make_float2(fmaxf(ma + tb7[wc0], 0.f), fmaxf(mb + tb7[wc1], 0.f));
}

// ---------------- K5: ff_lower 32-rows, 2 cols/thread + CSR fill ------------
// (round-16 measured-best shape: c = t&63 -> cols {c, c+64}; rh = t>>6 -> 8 rows)
__global__ __launch_bounds__(256) void k_ff_lower_fill(
    const float* __restrict__ feats, const float* __restrict__ ffw,
    const float* __restrict__ ffb, const float* __restrict__ lw,
    float* __restrict__ hw,
    const int* __restrict__ ei0, const int* __restrict__ ei1,
    const int* __restrict__ gei0, const int* __restrict__ gei1,
    int* __restrict__ cur1, int* __restrict__ esrc1,
    int* __restrict__ cur2, int* __restrict__ esrc2)
{
    __shared__ float fs[32 * 192];         // 24.5 KB
    __shared__ float h0s[32 * 128];        // 16 KB
    const int t = threadIdx.x;
    if (blockIdx.x >= 1024) {
        const int gid = (blockIdx.x - 1024) * 256 + t;
        if (gid < 2 * E1) {
            const int eb = gid >= E1;
            const int le = gid - (eb ? E1 : 0);
            const int* ei = eb ? ei1 : ei0;
            const int s = ei[le];
            const int d = ei[E1 + le];
            const int pos = atomicAdd(&cur1[(eb ? NROWS : 0) + d], 1);
            esrc1[pos] = s;
        } else {
            const int g2 = gid - 2 * E1;
            const int eb = g2 >= E2;
            const int le = g2 - (eb ? E2 : 0);
            const int* ei = eb ? gei1 : gei0;
            const int s = ei[le];
            const int d = ei[E2 + le];
            const int pos = atomicAdd(&cur2[(eb ? GROWS : 0) + d], 1);
            esrc2[pos] = s;
        }
        return;
    }
    const int nb = blockIdx.x >> 6;        // 0..15 (b-tile of 32 over 512)
    const int n  = blockIdx.x & 63;
    const int c  = t & 63;
    const int rh = t >> 6;                 // 0..3 -> rows rh*8..rh*8+7
    {
        float4* d4 = (float4*)fs;
        for (int i = t; i < 32 * 48; i += 256) {
            const int r = i / 48, c4 = i - r * 48;
            d4[i] = *(const float4*)(feats + ((size_t)(nb * 32 + r) * 64 + n) * 192 + c4 * 4);
        }
    }
    __syncthreads();
    // phase 1: h0 = relu(feats @ ffw + b), K=192
    {
        const float* w = ffw + (size_t)n * 192 * 128 + c;
        float acc[8][2];
        #pragma unroll
        for (int j = 0; j < 8; ++j) { acc[j][0] = 0.f; acc[j][1] = 0.f; }
        #pragma unroll 2
        for (int f = 0; f < 192; f += 4) {
            float wv[4][2];
            #pragma unroll
            for (int k = 0; k < 4; ++k) {
                wv[k][0] = w[(f + k) * 128];
                wv[k][1] = w[(f + k) * 128 + 64];
            }
            #pragma unroll
            for (int j = 0; j < 8; ++j) {
                const float4 xv = *(const float4*)(fs + (rh * 8 + j) * 192 + f);
                acc[j][0] = fmaf(xv.x, wv[0][0], acc[j][0]);
                acc[j][1] = fmaf(xv.x, wv[0][1], acc[j][1]);
                acc[j][0] = fmaf(xv.y, wv[1][0], acc[j][0]);
                acc[j][1] = fmaf(xv.y, wv[1][1], acc[j][1]);
                acc[j][0] = fmaf(xv.z, wv[2][0], acc[j][0]);
                acc[j][1] = fmaf(xv.z, wv[2][1], acc[j][1]);
                acc[j][0] = fmaf(xv.w, wv[3][0], acc[j][0]);
                acc[j][1] = fmaf(xv.w, wv[3][1], acc[j][1]);
            }
        }
        const float bias0 = ffb[n * 128 + c];
        const float bias1 = ffb[n * 128 + c + 64];
        #pragma unroll
        for (int j = 0; j < 8; ++j) {
            h0s[(rh * 8 + j) * 128 + c]      = fmaxf(acc[j][0] + bias0, 0.f);
            h0s[(rh * 8 + j) * 128 + c + 64] = fmaxf(acc[j][1] + bias1, 0.f);
        }
    }
    __syncthreads();
    // phase 2: hw = h0 @ lower_w, K=128
    {
        const float* w = lw + c;
        float acc[8][2];
        #pragma unroll
        for (int j = 0; j < 8; ++j) { acc[j][0] = 0.f; acc[j][1] = 0.f; }
        #pragma unroll 2
        for (int f = 0; f < 128; f += 4) {
            float wv[4][2];
            #pragma unroll
            for (int k = 0; k < 4; ++k) {
                wv[k][0] = w[(f + k) * 128];
                wv[k][1] = w[(f + k) * 128 + 64];
            }
            #pragma unroll
            for (int j = 0; j < 8; ++j) {
                const float4 xv = *(const float4*)(h0s + (rh * 8 + j) * 128 + f);
                acc[j][0] = fmaf(xv.x, wv[0][0], acc[j][0]);
                acc[j][1] = fmaf(xv.x, wv[0][1], acc[j][1]);
                acc[j][0] = fmaf(xv.y, wv[1][0], acc[j][0]);
                acc[j][1] = fmaf(xv.y, wv[1][1], acc[j][1]);
                acc[j][0] = fmaf(xv.z, wv[2][0], acc[j][0]);
                acc[j][1] = fmaf(xv.z, wv[2][1], acc[j][1]);
                acc[j][0] = fmaf(xv.w, wv[3][0], acc[j][0]);
                acc[j][1] = fmaf(xv.w, wv[3][1], acc[j][1]);
            }
        }
        #pragma unroll
        for (int j = 0; j < 8; ++j) {
            const int row = nb * 32 + rh * 8 + j;
            hw[((size_t)row * 64 + n) * 128 + c]      = acc[j][0];
            hw[((size_t)row * 64 + n) * 128 + c + 64] = acc[j][1];
        }
    }
}

// ---------------- CSR small kernels -----------------------------------------
__global__ void k_zero_i(int* __restrict__ p, int n) {
    const int i = blockIdx.x * blockDim.x + threadIdx.x;
    if (i < n) p[i] = 0;
}
__global__ __launch_bounds__(256) void k_scan_bsum_all(
    const int* __restrict__ cnt1, const int* __restrict__ cnt2,
    int* __restrict__ bsum1, int* __restrict__ bsum2)
{
    const int blk = blockIdx.x, t = threadIdx.x;
    const int* cnt; int* bsum; int lblk;
    if (blk < 32) { cnt = cnt1; bsum = bsum1; lblk = blk; }
    else          { cnt = cnt2; bsum = bsum2; lblk = blk - 32; }
    const int4 v = ((const int4*)cnt)[lblk * 256 + t];
    int s = v.x + v.y + v.z + v.w;
    #pragma unroll
    for (int off = 32; off > 0; off >>= 1) s += __shfl_down(s, off);
    __shared__ int wsum[4];
    if ((t & 63) == 0) wsum[t >> 6] = s;
    __syncthreads();
    if (t == 0) bsum[lblk] = wsum[0] + wsum[1] + wsum[2] + wsum[3];
}
__global__ __launch_bounds__(256) void k_scan_final_all(
    const int* __restrict__ cnt1, const int* __restrict__ bsum1,
    int* __restrict__ offs1, int* __restrict__ cur1, float* __restrict__ dinv1,
    const int* __restrict__ cnt2, const int* __restrict__ bsum2,
    int* __restrict__ offs2, int* __restrict__ cur2, float* __restrict__ dinv2)
{
    const int blk = blockIdx.x, t = threadIdx.x;
    const int* cnt; const int* bsum; int* offs; int* cur; float* dinv;
    int n, nb, lblk;
    if (blk < 32) { cnt = cnt1; bsum = bsum1; offs = offs1; cur = cur1; dinv = dinv1;
                    n = 2 * NROWS; nb = 32; lblk = blk; }
    else          { cnt = cnt2; bsum = bsum2; offs = offs2; cur = cur2; dinv = dinv2;
                    n = 2 * GROWS; nb = 8; lblk = blk - 32; }
    int base = 0;
    for (int i = 0; i < lblk; ++i) base += bsum[i];
    const int4 v = ((const int4*)cnt)[lblk * 256 + t];
    const int s = v.x + v.y + v.z + v.w;
    int sc = s;
    #pragma unroll
    for (int off = 1; off < 64; off <<= 1) {
        const int u = __shfl_up(sc, off);
        if ((t & 63) >= off) sc += u;
    }
    __shared__ int wsum[4];
    if ((t & 63) == 63) wsum[t >> 6] = sc;
    __syncthreads();
    int wbase = 0;
    for (int wv = 0; wv < (t >> 6); ++wv) wbase += wsum[wv];
    int o0 = base + wbase + sc - s;
    const int gi = lblk * 1024 + t * 4;
    offs[gi + 0] = o0; cur[gi + 0] = o0; dinv[gi + 0] = rsqrtf(1.f + (float)v.x); o0 += v.x;
    offs[gi + 1] = o0; cur[gi + 1] = o0; dinv[gi + 1] = rsqrtf(1.f + (float)v.y); o0 += v.y;
    offs[gi + 2] = o0; cur[gi + 2] = o0; dinv[gi + 2] = rsqrtf(1.f + (float)v.z); o0 += v.z;
    offs[gi + 3] = o0; cur[gi + 3] = o0; dinv[gi + 3] = rsqrtf(1.f + (float)v.w); o0 += v.w;
    if (lblk == nb - 1 && t == 255) offs[n] = o0;
}

// ---------------- GCN gather (combined 2n rows) -----------------------------
__global__ __launch_bounds__(128) void k_gcn_gather(
    const int* __restrict__ offs, const int* __restrict__ esrc,
    const float* __restrict__ hw, const float* __restrict__ dinv,
    const float* __restrict__ bias, float* __restrict__ out, int n)
{
    const int d = blockIdx.x;
    const int t = threadIdx.x;             // 128
    const int sbase = (d >= n) ? n : 0;
    const int e0 = offs[d], e1 = offs[d + 1];
    const float dd = dinv[d];
    float a0 = hw[(size_t)d * 128 + t] * dd;
    float a1 = 0.f, a2 = 0.f, a3 = 0.f;
    int j = e0;
    for (; j + 3 < e1; j += 4) {
        const int s0 = sbase + esrc[j],     s1 = sbase + esrc[j + 1];
        const int s2 = sbase + esrc[j + 2], s3 = sbase + esrc[j + 3];
        a0 = fmaf(hw[(size_t)s0 * 128 + t], dinv[s0], a0);
        a1 = fmaf(hw[(size_t)s1 * 128 + t], dinv[s1], a1);
        a2 = fmaf(hw[(size_t)s2 * 128 + t], dinv[s2], a2);
        a3 = fmaf(hw[(size_t)s3 * 128 + t], dinv[s3], a3);
    }
    for (; j < e1; ++j) {
        const int s = sbase + esrc[j];
        a0 = fmaf(hw[(size_t)s * 128 + t], dinv[s], a0);
    }
    const float acc = (a0 + a1) + (a2 + a3);
    out[(size_t)d * 128 + t] = fmaf(acc, dd, bias[t]);
}

// ---------------- fused agg(512->128) + upper(128x128) ---------------------
__global__ __launch_bounds__(256) void k_aggup(
    const float* __restrict__ h, const float* __restrict__ aggw,
    const float* __restrict__ aggb, const float* __restrict__ uw,
    float* __restrict__ hgw)
{
    const int bt = blockIdx.x >> 4;        // 0..127
    const int g  = blockIdx.x & 15;
    const int t  = threadIdx.x;
    const int o  = t & 127;
    const int hf = t >> 7;                 // 0..1
    __shared__ float fs[4 * 512];
    __shared__ float red[2][4][128];
    __shared__ float hgs[4][128];
    {
        const int b0 = bt * 4;
        float4* dst = (float4*)fs;
        for (int i = t; i < 4 * 128; i += 256) {
            const int r = i >> 7;
            const int q = i & 127;
            dst[i] = *(const float4*)(h + ((size_t)(b0 + r) * 64 + g * 4) * 128 + q * 4);
        }
    }
    __syncthreads();
    {
        const float* w = aggw + (size_t)g * 512 * 128 + (size_t)hf * 256 * 128 + o;
        float a0 = 0.f, a1 = 0.f, a2 = 0.f, a3 = 0.f;
        const float* x0 = fs + 0 * 512 + hf * 256;
        const float* x1 = fs + 1 * 512 + hf * 256;
        const float* x2 = fs + 2 * 512 + hf * 256;
        const float* x3 = fs + 3 * 512 + hf * 256;
        #pragma unroll 8
        for (int f = 0; f < 256; ++f) {
            const float wv = w[f * 128];
            a0 = fmaf(x0[f], wv, a0);
            a1 = fmaf(x1[f], wv, a1);
            a2 = fmaf(x2[f], wv, a2);
            a3 = fmaf(x3[f], wv, a3);
        }
        red[hf][0][o] = a0; red[hf][1][o] = a1; red[hf][2][o] = a2; red[hf][3][o] = a3;
    }
    __syncthreads();
    if (t < 128) {
        const float bias = aggb[g * 128 + t];
        #pragma unroll
        for (int r = 0; r < 4; ++r)
            hgs[r][t] = red[0][r][t] + red[1][r][t] + bias;
    }
    __syncthreads();
    {
        const float* w = uw + o;
        float a0 = 0.f, a1 = 0.f;
        #pragma unroll 2
        for (int f = 0; f < 128; f += 4) {
            const float w0 = w[(f + 0) * 128];
            const float w1 = w[(f + 1) * 128];
            const float w2 = w[(f + 2) * 128];
            const float w3_ = w[(f + 3) * 128];
            const float4 xv0 = *(const float4*)(&hgs[hf * 2 + 0][f]);
            const float4 xv1 = *(const float4*)(&hgs[hf * 2 + 1][f]);
            a0 = fmaf(xv0.x, w0, a0); a0 = fmaf(xv0.y, w1, a0);
            a0 = fmaf(xv0.z, w2, a0); a0 = fmaf(xv0.w, w3_, a0);
            a1 = fmaf(xv1.x, w0, a1); a1 = fmaf(xv1.y, w1, a1);
            a1 = fmaf(xv1.z, w2, a1); a1 = fmaf(xv1.w, w3_, a1);
        }
        const int r0g = (bt * 4 + hf * 2) * 16 + g;
        hgw[(size_t)r0g * 128 + o] = a0;
        hgw[(size_t)(r0g + 16) * 128 + o] = a1;
    }
}

// ---------------- fused gather2 + relu + disc(256->128,relu) ---------------
__global__ __launch_bounds__(256) void k_gdisc(
    const int* __restrict__ offs, const int* __restrict__ esrc,
    const float* __restrict__ hgw, const float* __restrict__ dinv,
    const float* __restrict__ ub,
    const float* __restrict__ dw, const float* __restrict__ db,
    float* __restrict__ dd)
{
    const int bt = blockIdx.x >> 4;        // 0..63
    const int g  = blockIdx.x & 15;
    const int t  = threadIdx.x;
    const int o  = t & 127;
    const int hf = t >> 7;
    __shared__ float fsA[2][8][128];
    __shared__ float fs[4][256];
    __shared__ float red[2][4][128];

    for (int r = 0; r < 8; ++r) {
        const int bi = r >> 1, eb = r & 1;
        const int sbase = eb ? GROWS : 0;
        const int drow = sbase + (bt * 4 + bi) * 16 + g;
        const int e0 = offs[drow], e1 = offs[drow + 1];
        float acc  = (hf == 0) ? hgw[(size_t)drow * 128 + o] * dinv[drow] : 0.f;
        float acc2 = 0.f;
        int jj = e0 + hf;
        for (; jj + 2 < e1; jj += 4) {
            const int s0 = sbase + esrc[jj];
            const int s1 = sbase + esrc[jj + 2];
            acc  = fmaf(hgw[(size_t)s0 * 128 + o], dinv[s0], acc);
            acc2 = fmaf(hgw[(size_t)s1 * 128 + o], dinv[s1], acc2);
        }
        for (; jj < e1; jj += 2) {
            const int s = sbase + esrc[jj];
            acc = fmaf(hgw[(size_t)s * 128 + o], dinv[s], acc);
        }
        fsA[hf][r][o] = acc + acc2;
    }
    __syncthreads();
    for (int idx = t; idx < 1024; idx += 256) {
        const int r = idx >> 7, oc = idx & 127;
        const int bi = r >> 1, eb = r & 1;
        const int sbase = eb ? GROWS : 0;
        const int drow = sbase + (bt * 4 + bi) * 16 + g;
        fs[bi][eb * 128 + oc] =
            fmaxf(fmaf(fsA[0][r][oc] + fsA[1][r][oc], dinv[drow], ub[oc]), 0.f);
    }
    __syncthreads();
    {
        const float* w = dw + (size_t)g * 256 * 128 + (size_t)hf * 128 * 128 + o;
        float a0 = 0.f, a1 = 0.f, a2 = 0.f, a3 = 0.f;
        const float* x0 = &fs[0][hf * 128];
        const float* x1 = &fs[1][hf * 128];
        const float* x2 = &fs[2][hf * 128];
        const float* x3 = &fs[3][hf * 128];
        #pragma unroll 8
        for (int f = 0; f < 128; ++f) {
            const float wv = w[f * 128];
            a0 = fmaf(x0[f], wv, a0);
            a1 = fmaf(x1[f], wv, a1);
            a2 = fmaf(x2[f], wv, a2);
            a3 = fmaf(x3[f], wv, a3);
        }
        red[hf][0][o] = a0; red[hf][1][o] = a1; red[hf][2][o] = a2; red[hf][3][o] = a3;
    }
    __syncthreads();
    if (t < 128) {
        const float bias = db[g * 128 + t];
        #pragma unroll
        for (int r = 0; r < 4; ++r) {
            const int b = bt * 4 + r;
            dd[(size_t)b * 2048 + g * 128 + t] =
                fmaxf(red[0][r][t] + red[1][r][t] + bias, 0.f);
        }
    }
}

// ---------------- final fc 2048->64 -----------------------------------------
__global__ __launch_bounds__(256) void k_fc(
    const float* __restrict__ dd, const float* __restrict__ fcw,
    const float* __restrict__ fcb, float* __restrict__ out)
{
    const int b = blockIdx.x;
    const int t = threadIdx.x;
    const int o = t & 63;
    const int k = t >> 6;
    __shared__ float ds[2048];
    __shared__ float red[4][64];
    for (int i = t; i < 2048; i += 256) ds[i] = dd[(size_t)b * 2048 + i];
    __syncthreads();
    const float* w  = fcw + (k * 512) * 64 + o;
    const float* xr = ds + k * 512;
    float a0 = 0.f, a1 = 0.f, a2 = 0.f, a3 = 0.f;
    #pragma unroll 4
    for (int f = 0; f < 512; f += 4) {
        a0 = fmaf(xr[f + 0], w[(f + 0) * 64], a0);
        a1 = fmaf(xr[f + 1], w[(f + 1) * 64], a1);
        a2 = fmaf(xr[f + 2], w[(f + 2) * 64], a2);
        a3 = fmaf(xr[f + 3], w[(f + 3) * 64], a3);
    }
    red[k][o] = (a0 + a1) + (a2 + a3);
    __syncthreads();
    if (t < 64)
        out[(size_t)b * 64 + t] = ((red[0][t] + red[1][t]) + (red[2][t] + red[3][t])) + fcb[t];
}

} // namespace

extern "C" void kernel_launch(void* const* d_in, const int* in_sizes, int n_in,
                              void* d_out, int out_size, void* d_ws, size_t ws_size,
                              hipStream_t stream)
{
    const float* x1 = (const float*)d_in[0];
    const float* x2 = (const float*)d_in[1];
    const int* ei0  = (const int*)d_in[2];
    const int* ei1  = (const int*)d_in[3];
    const int* gei0 = (const int*)d_in[4];
    const int* gei1 = (const int*)d_in[5];
    const float* conv_w3 = (const float*)d_in[6];
    const float* conv_b3 = (const float*)d_in[7];
    const float* conv_w5 = (const float*)d_in[8];
    const float* conv_b5 = (const float*)d_in[9];
    const float* conv_w7 = (const float*)d_in[10];
    const float* conv_b7 = (const float*)d_in[11];
    const float* tconv_w3 = (const float*)d_in[12];
    const float* tconv_b3 = (const float*)d_in[13];
    const float* tconv_w5 = (const float*)d_in[14];
    const float* tconv_b5 = (const float*)d_in[15];
    const float* tconv_w7 = (const float*)d_in[16];
    const float* tconv_b7 = (const float*)d_in[17];
    const float* ff_w    = (const float*)d_in[18];
    const float* ff_b    = (const float*)d_in[19];
    const float* lower_w = (const float*)d_in[20];
    const float* lower_b = (const float*)d_in[21];
    const float* upper_w = (const float*)d_in[22];
    const float* upper_b = (const float*)d_in[23];
    const float* agg_w   = (const float*)d_in[24];
    const float* agg_b   = (const float*)d_in[25];
    const float* disc_w  = (const float*)d_in[26];
    const float* disc_b  = (const float*)d_in[27];
    const float* fc_w    = (const float*)d_in[28];
    const float* fc_b    = (const float*)d_in[29];

    float* ws = (float*)d_ws;
    float* f_feats = ws;                          // 6291456
    float* f_hw    = ws + 10485760;               // 4194304
    float* f_gout  = ws + 14680064;               // 4194304
    float* f_hgw   = ws + 19922944;               // 1048576
    float* f_dd    = ws + 22020096;               // 524288
    float* f_dinv1 = ws + 22544384;               // 32768
    float* f_dinv2 = ws + 22577152;               // 8192
    int* ip    = (int*)(ws + 22585344);
    int* cnt1  = ip;                              // 32768
    int* cnt2  = cnt1 + 2 * NROWS;                // 8192
    int* offs1 = cnt2 + 2 * GROWS;                // 32769
    int* cur1  = offs1 + 2 * NROWS + 1;           // 32768
    int* esrc1 = cur1 + 2 * NROWS;                // 524288
    int* offs2 = esrc1 + 2 * E1;                  // 8193
    int* cur2  = offs2 + 2 * GROWS + 1;           // 8192
    int* esrc2 = cur2 + 2 * GROWS;                // 65536
    int* bsum1 = esrc2 + 2 * E2;                  // 32
    int* bsum2 = bsum1 + 32;                      // 8

    // 9 dispatches total
    k_zero_i<<<(2 * NROWS + 2 * GROWS) / 256, 256, 0, stream>>>(cnt1, 2 * NROWS + 2 * GROWS);
    k_conv_hist<<<2048 + (2 * E1 + 2 * E2) / 256, 256, 0, stream>>>(x1, x2,
        conv_w3, conv_b3, conv_w5, conv_b5, conv_w7, conv_b7,
        tconv_w3, tconv_b3, tconv_w5, tconv_b5, tconv_w7, tconv_b7, f_feats,
        ei0, ei1, gei0, gei1, cnt1, cnt2);
    k_scan_bsum_all<<<40, 256, 0, stream>>>(cnt1, cnt2, bsum1, bsum2);
    k_scan_final_all<<<40, 256, 0, stream>>>(cnt1, bsum1, offs1, cur1, f_dinv1,
                                             cnt2, bsum2, offs2, cur2, f_dinv2);
    k_ff_lower_fill<<<1024 + (2 * E1 + 2 * E2) / 256, 256, 0, stream>>>(
        f_feats, ff_w, ff_b, lower_w, f_hw,
        ei0, ei1, gei0, gei1, cur1, esrc1, cur2, esrc2);
    k_gcn_gather<<<2 * NROWS, 128, 0, stream>>>(offs1, esrc1, f_hw, f_dinv1,
                                                lower_b, f_gout, NROWS);
    k_aggup<<<2048, 256, 0, stream>>>(f_gout, agg_w, agg_b, upper_w, f_hgw);
    k_gdisc<<<1024, 256, 0, stream>>>(offs2, esrc2, f_hgw, f_dinv2, upper_b,
                                      disc_w, disc_b, f_dd);
    k_fc<<<Bn, 256, 0, stream>>>(f_dd, fc_w, fc_b, (float*)d_out);
}